// Round 7
// baseline (58.671 us; speedup 1.0000x reference)
//
#include <hip/hip_runtime.h>
#include <math.h>

#define NN   65536
#define DEGC 16
#define DD   64
#define DD2  128
#define BB   1024
#define NEGC 10
#define NROWS (2 * BB + NEGC)      // 2058
#define NEDGE (NROWS * DEGC)       // 32928
#define H1BLOCKS 512
#define H1WAVES  (H1BLOCKS * 4)    // 2048 = exactly co-resident at 2 waves/SIMD
#define CHUNK ((NEDGE + H1WAVES - 1) / H1WAVES)   // 17

__device__ __forceinline__ float tanh_fast(float x) {
    float t = __expf(2.0f * x);
    return 1.0f - 2.0f * __builtin_amdgcn_rcpf(t + 1.0f);
}

// ---------------------------------------------------------------------------
// K0: flatten the 3-deep index chain: nodes_e[e] = adj[node_of_row(e>>4)][e&15]
// ---------------------------------------------------------------------------
__global__ __launch_bounds__(256) void edges_kernel(
    const int* __restrict__ adj,
    const int* __restrict__ in1, const int* __restrict__ in2,
    const int* __restrict__ neg, int* __restrict__ nodes_e) {
    int e = blockIdx.x * 256 + threadIdx.x;
    if (e >= NEDGE) return;
    int r = e >> 4, k = e & 15;
    int node = (r < BB) ? in1[r] : (r < 2 * BB ? in2[r - BB] : neg[r - 2 * BB]);
    nodes_e[e] = adj[node * DEGC + k];
}

// ---------------------------------------------------------------------------
// K1: fused gather + GEMV1, 2-deep software-pipelined.
//   h1[e] = tanh([feat[n_e] | sum_k feat[adj[n_e][k]]] @ W1^T + b1)
// Lane j owns output j; W1 row j in 128 VGPRs. Per iteration: issue frow_i
// loads, reduce prefetched gather g_i -> LDS (wave-private) broadcast, issue
// gather for edge i+1, FMA phase B (csum) then phase A (frow), tanh, store.
// ---------------------------------------------------------------------------
__global__ __launch_bounds__(256) void hop1_fused(
    const float* __restrict__ feat, const int* __restrict__ adj,
    const int* __restrict__ nodes_e,
    const float* __restrict__ W1, const float* __restrict__ b1,
    float* __restrict__ h1) {

    __shared__ float wt[DD2 * 65];        // 33.3 KB, wt[i*65+j] = W1[j][i]
    __shared__ float4 cs4[4][16];         // 1 KB, wave-private csum rows

    int tid = threadIdx.x;
    #pragma unroll
    for (int t = 0; t < (DD * DD2) / 256; ++t) {
        int lin = t * 256 + tid;          // lin = j*128 + i
        int j = lin >> 7, i = lin & 127;
        wt[i * 65 + j] = W1[lin];
    }
    __syncthreads();

    int lane = tid & 63;
    int w = tid >> 6;
    float wreg[DD2];
    #pragma unroll
    for (int i = 0; i < DD2; ++i)
        wreg[i] = wt[i * 65 + lane];
    float bias = b1[lane];

    int wid = blockIdx.x * 4 + w;
    int e0 = wid * CHUNK;
    int e1 = min(e0 + CHUNK, NEDGE);
    if (e0 >= e1) return;                 // no barriers after this point

    float* csrow = (float*)&cs4[w][0];

    // prologue: gather for first edge in flight
    int n_cur = __builtin_amdgcn_readfirstlane(nodes_e[e0]);
    float g[DEGC];
    {
        const int* arow = adj + n_cur * DEGC;
        #pragma unroll
        for (int k2 = 0; k2 < DEGC; ++k2)
            g[k2] = feat[arow[k2] * DD + lane];
    }

    for (int e = e0; e < e1; ++e) {
        int enx = (e + 1 < e1) ? e + 1 : e;
        int n_nxt = __builtin_amdgcn_readfirstlane(nodes_e[enx]);

        // issue current self-row loads (consumed last, in phase A)
        const float* frow = feat + (size_t)n_cur * DD;
        float4 f[16];
        #pragma unroll
        for (int i4 = 0; i4 < 16; ++i4)
            f[i4] = *(const float4*)(frow + i4 * 4);

        // reduce prefetched gather (tree) -> wave-private LDS row
        float s;
        {
            float p[8];
            #pragma unroll
            for (int k2 = 0; k2 < 8; ++k2) p[k2] = g[2 * k2] + g[2 * k2 + 1];
            float q0 = (p[0] + p[1]) + (p[2] + p[3]);
            float q1 = (p[4] + p[5]) + (p[6] + p[7]);
            s = q0 + q1;
        }
        csrow[lane] = s;

        // issue next edge's gather loads (in flight during FMA phases)
        float g2[DEGC];
        {
            const int* arow2 = adj + n_nxt * DEGC;
            #pragma unroll
            for (int k2 = 0; k2 < DEGC; ++k2)
                g2[k2] = feat[arow2[k2] * DD + lane];
        }

        // phase B: csum half via LDS broadcast (short latency)
        float a0 = bias, a1 = 0.f, a2 = 0.f, a3 = 0.f;
        #pragma unroll
        for (int i4 = 0; i4 < 16; i4 += 4) {
            float4 c0 = cs4[w][i4 + 0];
            float4 c1 = cs4[w][i4 + 1];
            float4 c2 = cs4[w][i4 + 2];
            float4 c3 = cs4[w][i4 + 3];
            a0 += c0.x * wreg[DD + (i4 + 0) * 4 + 0] + c0.y * wreg[DD + (i4 + 0) * 4 + 1]
                + c0.z * wreg[DD + (i4 + 0) * 4 + 2] + c0.w * wreg[DD + (i4 + 0) * 4 + 3];
            a1 += c1.x * wreg[DD + (i4 + 1) * 4 + 0] + c1.y * wreg[DD + (i4 + 1) * 4 + 1]
                + c1.z * wreg[DD + (i4 + 1) * 4 + 2] + c1.w * wreg[DD + (i4 + 1) * 4 + 3];
            a2 += c2.x * wreg[DD + (i4 + 2) * 4 + 0] + c2.y * wreg[DD + (i4 + 2) * 4 + 1]
                + c2.z * wreg[DD + (i4 + 2) * 4 + 2] + c2.w * wreg[DD + (i4 + 2) * 4 + 3];
            a3 += c3.x * wreg[DD + (i4 + 3) * 4 + 0] + c3.y * wreg[DD + (i4 + 3) * 4 + 1]
                + c3.z * wreg[DD + (i4 + 3) * 4 + 2] + c3.w * wreg[DD + (i4 + 3) * 4 + 3];
        }
        // phase A: self-feat half (frow loads have had time to land)
        #pragma unroll
        for (int i4 = 0; i4 < 16; i4 += 4) {
            float4 c0 = f[i4 + 0], c1 = f[i4 + 1], c2 = f[i4 + 2], c3 = f[i4 + 3];
            a0 += c0.x * wreg[(i4 + 0) * 4 + 0] + c0.y * wreg[(i4 + 0) * 4 + 1]
                + c0.z * wreg[(i4 + 0) * 4 + 2] + c0.w * wreg[(i4 + 0) * 4 + 3];
            a1 += c1.x * wreg[(i4 + 1) * 4 + 0] + c1.y * wreg[(i4 + 1) * 4 + 1]
                + c1.z * wreg[(i4 + 1) * 4 + 2] + c1.w * wreg[(i4 + 1) * 4 + 3];
            a2 += c2.x * wreg[(i4 + 2) * 4 + 0] + c2.y * wreg[(i4 + 2) * 4 + 1]
                + c2.z * wreg[(i4 + 2) * 4 + 2] + c2.w * wreg[(i4 + 2) * 4 + 3];
            a3 += c3.x * wreg[(i4 + 3) * 4 + 0] + c3.y * wreg[(i4 + 3) * 4 + 1]
                + c3.z * wreg[(i4 + 3) * 4 + 2] + c3.w * wreg[(i4 + 3) * 4 + 3];
        }
        float acc = (a0 + a1) + (a2 + a3);
        h1[(size_t)e * DD + lane] = tanh_fast(acc);

        #pragma unroll
        for (int k2 = 0; k2 < DEGC; ++k2) g[k2] = g2[k2];
        n_cur = n_nxt;
    }
}

// ---------------------------------------------------------------------------
// K2: fused sum16 + GEMV2 + normalize (unchanged from R6 — not the bottleneck)
// ---------------------------------------------------------------------------
__global__ __launch_bounds__(256) void hop2_fused(
    const float* __restrict__ feat, const float* __restrict__ h1,
    const int* __restrict__ in1, const int* __restrict__ in2,
    const int* __restrict__ neg,
    const float* __restrict__ W2, const float* __restrict__ b2,
    float* __restrict__ out) {

    __shared__ float4 q2[4096];           // 64 KB
    __shared__ float4 cs4[8][16];         // 2 KB

    int tid = threadIdx.x;
    {
        int j = tid & 127, g0 = tid >> 7;
        #pragma unroll
        for (int g = 0; g < 16; ++g) {
            int i4 = g0 * 16 + g;
            q2[(i4 << 7) | j] = *(const float4*)(W2 + j * DD2 + (i4 << 2));
        }
    }

    int lane = tid & 63;
    int w = tid >> 6;
    int r0 = blockIdx.x * 8 + w * 2;
    int r1 = r0 + 1;
    bool a0 = r0 < NROWS, a1 = r1 < NROWS;

    #pragma unroll
    for (int m = 0; m < 2; ++m) {
        int r = r0 + m;
        if (r < NROWS) {
            const float* base = h1 + (size_t)r * DEGC * DD;
            float s = 0.f;
            #pragma unroll
            for (int k = 0; k < DEGC; ++k)
                s += base[k * DD + lane];
            ((float*)&cs4[w * 2 + m][0])[lane] = s;
        }
    }
    __syncthreads();

    int node0 = a0 ? ((r0 < BB) ? in1[r0] : (r0 < 2 * BB ? in2[r0 - BB] : neg[r0 - 2 * BB])) : 0;
    int node1 = a1 ? ((r1 < BB) ? in1[r1] : (r1 < 2 * BB ? in2[r1 - BB] : neg[r1 - 2 * BB])) : node0;
    node0 = __builtin_amdgcn_readfirstlane(node0);
    node1 = __builtin_amdgcn_readfirstlane(node1);
    const float* cf0 = feat + node0 * DD;
    const float* cf1 = feat + node1 * DD;

    float A0 = b2[lane], B0 = b2[DD + lane];
    float A1 = A0, B1 = B0;

    #pragma unroll
    for (int i4 = 0; i4 < 16; ++i4) {
        float4 wA = q2[(i4 << 7) | lane];
        float4 wB = q2[(i4 << 7) | (64 + lane)];
        float4 c0 = *(const float4*)(cf0 + (i4 << 2));
        float4 c1 = *(const float4*)(cf1 + (i4 << 2));
        A0 += c0.x * wA.x + c0.y * wA.y + c0.z * wA.z + c0.w * wA.w;
        B0 += c0.x * wB.x + c0.y * wB.y + c0.z * wB.z + c0.w * wB.w;
        A1 += c1.x * wA.x + c1.y * wA.y + c1.z * wA.z + c1.w * wA.w;
        B1 += c1.x * wB.x + c1.y * wB.y + c1.z * wB.z + c1.w * wB.w;
    }
    #pragma unroll
    for (int i4 = 0; i4 < 16; ++i4) {
        float4 wA = q2[((16 + i4) << 7) | lane];
        float4 wB = q2[((16 + i4) << 7) | (64 + lane)];
        float4 c0 = cs4[w * 2 + 0][i4];
        float4 c1 = cs4[w * 2 + 1][i4];
        A0 += c0.x * wA.x + c0.y * wA.y + c0.z * wA.z + c0.w * wA.w;
        B0 += c0.x * wB.x + c0.y * wB.y + c0.z * wB.z + c0.w * wB.w;
        A1 += c1.x * wA.x + c1.y * wA.y + c1.z * wA.z + c1.w * wA.w;
        B1 += c1.x * wB.x + c1.y * wB.y + c1.z * wB.z + c1.w * wB.w;
    }

    if (a0) {
        float ss = A0 * A0 + B0 * B0;
        #pragma unroll
        for (int off = 32; off > 0; off >>= 1) ss += __shfl_xor(ss, off, 64);
        float inv = 1.0f / fmaxf(sqrtf(ss), 1e-12f);
        out[r0 * DD2 + lane]      = A0 * inv;
        out[r0 * DD2 + DD + lane] = B0 * inv;
    }
    if (a1) {
        float ss = A1 * A1 + B1 * B1;
        #pragma unroll
        for (int off = 32; off > 0; off >>= 1) ss += __shfl_xor(ss, off, 64);
        float inv = 1.0f / fmaxf(sqrtf(ss), 1e-12f);
        out[r1 * DD2 + lane]      = A1 * inv;
        out[r1 * DD2 + DD + lane] = B1 * inv;
    }
}

// ---------------------------------------------------------------------------
extern "C" void kernel_launch(void* const* d_in, const int* in_sizes, int n_in,
                              void* d_out, int out_size, void* d_ws, size_t ws_size,
                              hipStream_t stream) {
    const float* feat = (const float*)d_in[0];
    const int*   adj  = (const int*)d_in[1];
    const int*   in1  = (const int*)d_in[2];
    const int*   in2  = (const int*)d_in[3];
    const int*   neg  = (const int*)d_in[4];
    const float* W1   = (const float*)d_in[5];
    const float* b1   = (const float*)d_in[6];
    const float* W2   = (const float*)d_in[7];
    const float* b2   = (const float*)d_in[8];
    float* out = (float*)d_out;

    float* h1      = (float*)d_ws;                            // 8.43 MB
    int*   nodes_e = (int*)((char*)d_ws + (size_t)NEDGE * DD * sizeof(float));

    edges_kernel<<<(NEDGE + 255) / 256, 256, 0, stream>>>(adj, in1, in2, neg, nodes_e);
    hop1_fused<<<H1BLOCKS, 256, 0, stream>>>(feat, adj, nodes_e, W1, b1, h1);
    hop2_fused<<<(NROWS + 7) / 8, 256, 0, stream>>>(
        feat, h1, in1, in2, neg, W2, b2, out);
}